// Round 5
// baseline (11217.038 us; speedup 1.0000x reference)
//
#include <hip/hip_runtime.h>
#include <stdint.h>

#define TT 4096
#define HH 512
#define GG 2048      // 4*H
#define NS 16        // workgroups (slices) per LSTM chain
#define HSTRIDE 8    // u64 stride per h value (64B line each -> slice spread)

typedef unsigned long long u64;

__device__ __forceinline__ float sigm(float x) { return 1.0f / (1.0f + __expf(-x)); }
__device__ __forceinline__ float tanh_fast(float x) {
    x = fminf(20.0f, fmaxf(-20.0f, x));
    float e = __expf(2.0f * x);
    return (e - 1.0f) / (e + 1.0f);
}

// ---------------------------------------------------------------------------
// xw = relu([word_emb[w]; pos_emb[p]] @ W^T + b), W: [512, 332]
__global__ __launch_bounds__(256) void k_xw(
    const int* __restrict__ words, const int* __restrict__ pos,
    const float* __restrict__ wemb, const float* __restrict__ pemb,
    const float* __restrict__ W, const float* __restrict__ b,
    float* __restrict__ out)
{
    __shared__ float xr[8][336];
    const int t0 = blockIdx.x * 8, tid = threadIdx.x;
    for (int s = 0; s < 8; ++s) {
        int w = words[t0 + s], p = pos[t0 + s];
        for (int i = tid; i < 332; i += 256)
            xr[s][i] = (i < 300) ? wemb[(size_t)w * 300 + i] : pemb[p * 32 + (i - 300)];
    }
    __syncthreads();
    const int o1 = tid, o2 = tid + 256;
    float acc[8][2] = {};
    for (int k = 0; k < 332; ++k) {
        float wa = W[(size_t)o1 * 332 + k];
        float wb = W[(size_t)o2 * 332 + k];
#pragma unroll
        for (int s = 0; s < 8; ++s) {
            float x = xr[s][k];
            acc[s][0] += wa * x;
            acc[s][1] += wb * x;
        }
    }
#pragma unroll
    for (int s = 0; s < 8; ++s) {
        out[(size_t)(t0 + s) * 512 + o1] = fmaxf(acc[s][0] + b[o1], 0.0f);
        out[(size_t)(t0 + s) * 512 + o2] = fmaxf(acc[s][1] + b[o2], 0.0f);
    }
}

// xa = relu(act_emb[a] @ W^T + b), W: [512, 64]
__global__ __launch_bounds__(256) void k_xa(
    const int* __restrict__ acts, const float* __restrict__ aemb,
    const float* __restrict__ W, const float* __restrict__ b,
    float* __restrict__ out)
{
    __shared__ float xr[8][68];
    const int t0 = blockIdx.x * 8, tid = threadIdx.x;
    for (int s = 0; s < 8; ++s) {
        int a = acts[t0 + s];
        if (tid < 64) xr[s][tid] = aemb[(size_t)a * 64 + tid];
    }
    __syncthreads();
    const int o1 = tid, o2 = tid + 256;
    float acc[8][2] = {};
    for (int k = 0; k < 64; ++k) {
        float wa = W[(size_t)o1 * 64 + k];
        float wb = W[(size_t)o2 * 64 + k];
#pragma unroll
        for (int s = 0; s < 8; ++s) {
            float x = xr[s][k];
            acc[s][0] += wa * x;
            acc[s][1] += wb * x;
        }
    }
#pragma unroll
    for (int s = 0; s < 8; ++s) {
        out[(size_t)(t0 + s) * 512 + o1] = fmaxf(acc[s][0] + b[o1], 0.0f);
        out[(size_t)(t0 + s) * 512 + o2] = fmaxf(acc[s][1] + b[o2], 0.0f);
    }
}

// ---------------------------------------------------------------------------
// C[M,N] = A[M,K] * B[N,K]^T + b1[N] (+ b2[N]); op==1 -> tanh epilogue.
__global__ __launch_bounds__(256) void gemm_nt(
    const float* __restrict__ A, const float* __restrict__ B, float* __restrict__ C,
    const float* __restrict__ b1, const float* __restrict__ b2,
    int M, int N, int K, int op)
{
    __shared__ __align__(16) float As[16][68];
    __shared__ __align__(16) float Bs[16][68];
    const int tid = threadIdx.x;
    const int bm = blockIdx.y * 64, bn = blockIdx.x * 64;
    const int lr = tid >> 2, lc = tid & 3;
    const int tm = tid & 15, tn = tid >> 4;
    float acc[4][4] = {};
    for (int k0 = 0; k0 < K; k0 += 16) {
        float4 a4 = *(const float4*)(A + (size_t)(bm + lr) * K + k0 + lc * 4);
        float4 b4 = *(const float4*)(B + (size_t)(bn + lr) * K + k0 + lc * 4);
        As[lc * 4 + 0][lr] = a4.x; As[lc * 4 + 1][lr] = a4.y;
        As[lc * 4 + 2][lr] = a4.z; As[lc * 4 + 3][lr] = a4.w;
        Bs[lc * 4 + 0][lr] = b4.x; Bs[lc * 4 + 1][lr] = b4.y;
        Bs[lc * 4 + 2][lr] = b4.z; Bs[lc * 4 + 3][lr] = b4.w;
        __syncthreads();
#pragma unroll
        for (int k = 0; k < 16; ++k) {
            const float4 av = *(const float4*)&As[k][tm * 4];
            const float4 bv = *(const float4*)&Bs[k][tn * 4];
            acc[0][0] += av.x * bv.x; acc[0][1] += av.x * bv.y; acc[0][2] += av.x * bv.z; acc[0][3] += av.x * bv.w;
            acc[1][0] += av.y * bv.x; acc[1][1] += av.y * bv.y; acc[1][2] += av.y * bv.z; acc[1][3] += av.y * bv.w;
            acc[2][0] += av.z * bv.x; acc[2][1] += av.z * bv.y; acc[2][2] += av.z * bv.z; acc[2][3] += av.z * bv.w;
            acc[3][0] += av.w * bv.x; acc[3][1] += av.w * bv.y; acc[3][2] += av.w * bv.z; acc[3][3] += av.w * bv.w;
        }
        __syncthreads();
    }
#pragma unroll
    for (int i = 0; i < 4; ++i) {
        const int r = bm + tm * 4 + i;
#pragma unroll
        for (int j = 0; j < 4; ++j) {
            const int cc = bn + tn * 4 + j;
            float v = acc[i][j] + b1[cc];
            if (b2) v += b2[cc];
            if (op == 1) v = tanh_fast(v);
            C[(size_t)r * N + cc] = v;
        }
    }
}

// ---------------------------------------------------------------------------
// Fence-free dataflow LSTM scan, one barrier per step.
// 3 chains x 16 slices = 48 WGs of 1024 threads.
// h values are tagged (epoch<<32|f32_bits) u64 atomics at agent scope, ONE
// VALUE PER 64B LINE (HSTRIDE=8) so polls/stores spread across L3 slices.
// Only waves 0-1 poll (128 lanes x 4 values); each wave independently
// detects its half and writes it to LDS; the step barrier joins them.
#define LDW(i) float4 q##i = wp[i];
#define SPL(i) float a##i##x = q##i.x, a##i##y = q##i.y, a##i##z = q##i.z, a##i##w = q##i.w;
#define PIN(i) asm volatile("" : "+v"(a##i##x), "+v"(a##i##y), "+v"(a##i##z), "+v"(a##i##w));
#define DOT(i) { float4 hv = hq[i]; \
    acc = fmaf(a##i##x, hv.x, acc); acc = fmaf(a##i##y, hv.y, acc); \
    acc = fmaf(a##i##z, hv.z, acc); acc = fmaf(a##i##w, hv.w, acc); }

__global__ __launch_bounds__(1024, 4) void scan_kernel(
    const float* __restrict__ gx,   // [3][T][2048] x-part + both biases
    const float* __restrict__ whh0, const float* __restrict__ whh1, const float* __restrict__ whh2,
    const float* __restrict__ h00, const float* __restrict__ h01, const float* __restrict__ h02,
    const float* __restrict__ c00, const float* __restrict__ c01, const float* __restrict__ c02,
    u64* __restrict__ hbuf,         // [2][3][512][HSTRIDE] tagged, pre-zeroed
    float* __restrict__ htop)       // [T][1536] pre-update h (stk|buf|hist)
{
    const int chain = blockIdx.x / NS;
    const int slice = blockIdx.x % NS;
    const int tid = threadIdx.x;
    const int out_j = tid >> 5;       // 0..31
    const int gate  = (tid >> 3) & 3; // 0..3 (i,f,g,o)
    const int k     = tid & 7;        // 64-col chunk
    const int row   = gate * HH + slice * 32 + out_j;   // gate row in whh
    const int lane  = tid & 63;
    const int lbase = lane & 32;

    const float* whh = (chain == 0) ? whh0 : (chain == 1) ? whh1 : whh2;
    const float* h0  = (chain == 0) ? h00  : (chain == 1) ? h01  : h02;
    const float* c0  = (chain == 0) ? c00  : (chain == 1) ? c01  : c02;
    const float* gxc = gx + (size_t)chain * TT * GG;

    // weight slice -> 64 named scalar floats
    const float4* wp = (const float4*)(whh + (size_t)row * HH + k * 64);
    LDW(0) LDW(1) LDW(2) LDW(3) LDW(4) LDW(5) LDW(6) LDW(7)
    LDW(8) LDW(9) LDW(10) LDW(11) LDW(12) LDW(13) LDW(14) LDW(15)
    SPL(0) SPL(1) SPL(2) SPL(3) SPL(4) SPL(5) SPL(6) SPL(7)
    SPL(8) SPL(9) SPL(10) SPL(11) SPL(12) SPL(13) SPL(14) SPL(15)

    float c_reg = 0.0f;
    if ((tid & 31) == 0) {
        c_reg = c0[slice * 32 + out_j];
        float hv = h0[slice * 32 + out_j];
        u64 pv = ((u64)1u << 32) | (u64)__float_as_uint(hv);   // tag 1 = ready for t=0
        __hip_atomic_store(&hbuf[((size_t)chain * HH + slice * 32 + out_j) * HSTRIDE], pv,
                           __ATOMIC_RELAXED, __HIP_MEMORY_SCOPE_AGENT);
        htop[(size_t)chain * HH + slice * 32 + out_j] = hv;    // htop[0]
    }

    __shared__ float h_lds[2][8 * 68];   // parity double buffer, 68-float chunk stride

    for (int t = 0; t < TT; ++t) {
        // pin weights in VGPRs/AGPRs across the loop (defeat load-sinking)
        PIN(0) PIN(1) PIN(2) PIN(3) PIN(4) PIN(5) PIN(6) PIN(7)
        PIN(8) PIN(9) PIN(10) PIN(11) PIN(12) PIN(13) PIN(14) PIN(15)
        const int par = t & 1;

        // gx prefetch (k==0 lanes; consumed after the reduce)
        float gxv = 0.0f;
        if (k == 0) gxv = gxc[(size_t)t * GG + row];

        // poll: waves 0-1 only; lane L owns values {L, L+128, L+256, L+384}
        if (tid < 128) {
            const u64* base = hbuf + (size_t)(par * 3 + chain) * HH * HSTRIDE;
            const unsigned need = (unsigned)(t + 1);
            u64 p0, p1, p2, p3;
            for (;;) {
                p0 = __hip_atomic_load(base + (size_t)(tid      ) * HSTRIDE, __ATOMIC_RELAXED, __HIP_MEMORY_SCOPE_AGENT);
                p1 = __hip_atomic_load(base + (size_t)(tid + 128) * HSTRIDE, __ATOMIC_RELAXED, __HIP_MEMORY_SCOPE_AGENT);
                p2 = __hip_atomic_load(base + (size_t)(tid + 256) * HSTRIDE, __ATOMIC_RELAXED, __HIP_MEMORY_SCOPE_AGENT);
                p3 = __hip_atomic_load(base + (size_t)(tid + 384) * HSTRIDE, __ATOMIC_RELAXED, __HIP_MEMORY_SCOPE_AGENT);
                int ok = (unsigned)(p0 >> 32) >= need && (unsigned)(p1 >> 32) >= need &&
                         (unsigned)(p2 >> 32) >= need && (unsigned)(p3 >> 32) >= need;
                if (__all(ok)) break;
            }
            h_lds[par][((tid      ) >> 6) * 68 + (tid & 63)]        = __uint_as_float((unsigned)p0);
            h_lds[par][((tid + 128) >> 6) * 68 + (tid & 63)]        = __uint_as_float((unsigned)p1);
            h_lds[par][((tid + 256) >> 6) * 68 + (tid & 63)]        = __uint_as_float((unsigned)p2);
            h_lds[par][((tid + 384) >> 6) * 68 + (tid & 63)]        = __uint_as_float((unsigned)p3);
        }
        __syncthreads();   // the ONLY barrier per step

        // dot: row x h-chunk (64 cols) from LDS
        const float4* hq = (const float4*)(&h_lds[par][k * 68]);
        float acc = 0.0f;
        DOT(0) DOT(1) DOT(2) DOT(3) DOT(4) DOT(5) DOT(6) DOT(7)
        DOT(8) DOT(9) DOT(10) DOT(11) DOT(12) DOT(13) DOT(14) DOT(15)
        // butterfly over k (lanes ...+0..7)
        acc += __shfl_xor(acc, 1);
        acc += __shfl_xor(acc, 2);
        acc += __shfl_xor(acc, 4);
        if (k == 0) acc += gxv;
        // gather the 4 gate sums into the gate-0 lane (same wave)
        float gf = __shfl(acc, lbase + 8);
        float gg = __shfl(acc, lbase + 16);
        float go = __shfl(acc, lbase + 24);
        if ((tid & 31) == 0) {
            float c2 = sigm(gf) * c_reg + sigm(acc) * tanh_fast(gg);
            float h2 = sigm(go) * tanh_fast(c2);
            c_reg = c2;
            u64 pv = ((u64)(unsigned)(t + 2) << 32) | (u64)__float_as_uint(h2);
            __hip_atomic_store(&hbuf[((size_t)(((t + 1) & 1) * 3 + chain) * HH + slice * 32 + out_j) * HSTRIDE],
                               pv, __ATOMIC_RELAXED, __HIP_MEMORY_SCOPE_AGENT);
            if (t + 1 < TT)
                htop[(size_t)(t + 1) * 1536 + chain * HH + slice * 32 + out_j] = h2;
        }
    }
}

// ---------------------------------------------------------------------------
// per-row logits + log_softmax
__global__ __launch_bounds__(128) void k_logp(
    const float* __restrict__ summ, const float* __restrict__ Wo,
    const float* __restrict__ bo, float* __restrict__ out)
{
    __shared__ float srow[512];
    __shared__ float z[104];
    __shared__ float red[2];
    const int t = blockIdx.x, tid = threadIdx.x;
    ((float4*)srow)[tid] = ((const float4*)(summ + (size_t)t * 512))[tid];
    __syncthreads();
    if (tid < 100) {
        float a = bo[tid];
        const float* wr = Wo + (size_t)tid * 512;
        for (int k = 0; k < 512; k += 4)
            a += wr[k] * srow[k] + wr[k + 1] * srow[k + 1] + wr[k + 2] * srow[k + 2] + wr[k + 3] * srow[k + 3];
        z[tid] = a;
    }
    __syncthreads();
    if (tid < 64) {
        float m = z[tid];
        if (tid + 64 < 100) m = fmaxf(m, z[tid + 64]);
#pragma unroll
        for (int off = 32; off >= 1; off >>= 1) m = fmaxf(m, __shfl_xor(m, off, 64));
        float e = __expf(z[tid] - m) + ((tid + 64 < 100) ? __expf(z[tid + 64] - m) : 0.0f);
#pragma unroll
        for (int off = 32; off >= 1; off >>= 1) e += __shfl_xor(e, off, 64);
        if (tid == 0) { red[0] = m; red[1] = __logf(e); }
    }
    __syncthreads();
    if (tid < 100) out[(size_t)t * 100 + tid] = z[tid] - red[0] - red[1];
}

// ---------------------------------------------------------------------------
extern "C" void kernel_launch(void* const* d_in, const int* in_sizes, int n_in,
                              void* d_out, int out_size, void* d_ws, size_t ws_size,
                              hipStream_t stream)
{
    const int* words = (const int*)d_in[0];
    const int* pos   = (const int*)d_in[1];
    const int* acts  = (const int*)d_in[2];
    const float* wemb  = (const float*)d_in[3];
    const float* pemb  = (const float*)d_in[4];
    const float* aemb  = (const float*)d_in[5];
    const float* w2e_w = (const float*)d_in[6];
    const float* w2e_b = (const float*)d_in[7];
    const float* a2e_w = (const float*)d_in[8];
    const float* a2e_b = (const float*)d_in[9];
    const float* sum_w = (const float*)d_in[28];
    const float* sum_b = (const float*)d_in[29];
    const float* out_w = (const float*)d_in[30];
    const float* out_b = (const float*)d_in[31];

    float* ws = (float*)d_ws;
    float* xw   = ws;                                   // [4096*512]
    float* xa   = xw + (size_t)TT * HH;                 // [4096*512]
    float* gxp  = xa + (size_t)TT * HH;                 // [3][4096][2048]
    float* htop = gxp + (size_t)3 * TT * GG;            // [4096][1536]
    u64*   hbuf = (u64*)(htop + (size_t)TT * 3 * HH);   // [2][3][512][HSTRIDE]
    float* summary = xw;                                // alias: xw dead after Gx GEMMs

    (void)hipMemsetAsync(hbuf, 0, (size_t)2 * 3 * HH * HSTRIDE * sizeof(u64), stream);

    // Phase A: input projections
    k_xw<<<dim3(TT / 8), dim3(256), 0, stream>>>(words, pos, wemb, pemb, w2e_w, w2e_b, xw);
    k_xa<<<dim3(TT / 8), dim3(256), 0, stream>>>(acts, aemb, a2e_w, a2e_b, xa);

    // Phase A: Gx[c] = x_c @ wih_c^T + (bih_c + bhh_c)
    dim3 g2(GG / 64, TT / 64);
    gemm_nt<<<g2, dim3(256), 0, stream>>>(xw, (const float*)d_in[10], gxp,
                                          (const float*)d_in[12], (const float*)d_in[13],
                                          TT, GG, HH, 0);
    gemm_nt<<<g2, dim3(256), 0, stream>>>(xw, (const float*)d_in[16], gxp + (size_t)TT * GG,
                                          (const float*)d_in[18], (const float*)d_in[19],
                                          TT, GG, HH, 0);
    gemm_nt<<<g2, dim3(256), 0, stream>>>(xa, (const float*)d_in[22], gxp + (size_t)2 * TT * GG,
                                          (const float*)d_in[24], (const float*)d_in[25],
                                          TT, GG, HH, 0);

    // Phase B: dataflow scan (48 blocks of 1024)
    scan_kernel<<<dim3(3 * NS), dim3(1024), 0, stream>>>(
        gxp,
        (const float*)d_in[11], (const float*)d_in[17], (const float*)d_in[23],
        (const float*)d_in[14], (const float*)d_in[20], (const float*)d_in[26],
        (const float*)d_in[15], (const float*)d_in[21], (const float*)d_in[27],
        hbuf, htop);

    // Phase C: summary = tanh(Htop @ sum_w^T + sum_b); then logits + log_softmax
    dim3 g3(HH / 64, TT / 64);
    gemm_nt<<<g3, dim3(256), 0, stream>>>(htop, sum_w, summary, sum_b, nullptr,
                                          TT, HH, 3 * HH, 1);
    k_logp<<<dim3(TT), dim3(128), 0, stream>>>(summary, out_w, out_b, (float*)d_out);
}

// Round 9
// 7862.660 us; speedup vs baseline: 1.4266x; 1.4266x over previous
//
#include <hip/hip_runtime.h>
#include <stdint.h>

#define TT 4096
#define HH 512
#define GG 2048      // 4*H
#define NS 32        // workgroups (slices) per LSTM chain

typedef unsigned long long u64;

__device__ __forceinline__ float sigm(float x) { return 1.0f / (1.0f + __expf(-x)); }
__device__ __forceinline__ float tanh_fast(float x) {
    x = fminf(20.0f, fmaxf(-20.0f, x));
    float e = __expf(2.0f * x);
    return (e - 1.0f) / (e + 1.0f);
}

// ---------------------------------------------------------------------------
// xw = relu([word_emb[w]; pos_emb[p]] @ W^T + b), W: [512, 332]
__global__ __launch_bounds__(256) void k_xw(
    const int* __restrict__ words, const int* __restrict__ pos,
    const float* __restrict__ wemb, const float* __restrict__ pemb,
    const float* __restrict__ W, const float* __restrict__ b,
    float* __restrict__ out)
{
    __shared__ float xr[8][336];
    const int t0 = blockIdx.x * 8, tid = threadIdx.x;
    for (int s = 0; s < 8; ++s) {
        int w = words[t0 + s], p = pos[t0 + s];
        for (int i = tid; i < 332; i += 256)
            xr[s][i] = (i < 300) ? wemb[(size_t)w * 300 + i] : pemb[p * 32 + (i - 300)];
    }
    __syncthreads();
    const int o1 = tid, o2 = tid + 256;
    float acc[8][2] = {};
    for (int k = 0; k < 332; ++k) {
        float wa = W[(size_t)o1 * 332 + k];
        float wb = W[(size_t)o2 * 332 + k];
#pragma unroll
        for (int s = 0; s < 8; ++s) {
            float x = xr[s][k];
            acc[s][0] += wa * x;
            acc[s][1] += wb * x;
        }
    }
#pragma unroll
    for (int s = 0; s < 8; ++s) {
        out[(size_t)(t0 + s) * 512 + o1] = fmaxf(acc[s][0] + b[o1], 0.0f);
        out[(size_t)(t0 + s) * 512 + o2] = fmaxf(acc[s][1] + b[o2], 0.0f);
    }
}

// xa = relu(act_emb[a] @ W^T + b), W: [512, 64]
__global__ __launch_bounds__(256) void k_xa(
    const int* __restrict__ acts, const float* __restrict__ aemb,
    const float* __restrict__ W, const float* __restrict__ b,
    float* __restrict__ out)
{
    __shared__ float xr[8][68];
    const int t0 = blockIdx.x * 8, tid = threadIdx.x;
    for (int s = 0; s < 8; ++s) {
        int a = acts[t0 + s];
        if (tid < 64) xr[s][tid] = aemb[(size_t)a * 64 + tid];
    }
    __syncthreads();
    const int o1 = tid, o2 = tid + 256;
    float acc[8][2] = {};
    for (int k = 0; k < 64; ++k) {
        float wa = W[(size_t)o1 * 64 + k];
        float wb = W[(size_t)o2 * 64 + k];
#pragma unroll
        for (int s = 0; s < 8; ++s) {
            float x = xr[s][k];
            acc[s][0] += wa * x;
            acc[s][1] += wb * x;
        }
    }
#pragma unroll
    for (int s = 0; s < 8; ++s) {
        out[(size_t)(t0 + s) * 512 + o1] = fmaxf(acc[s][0] + b[o1], 0.0f);
        out[(size_t)(t0 + s) * 512 + o2] = fmaxf(acc[s][1] + b[o2], 0.0f);
    }
}

// ---------------------------------------------------------------------------
// C[M,N] = A[M,K] * B[N,K]^T + b1[N] (+ b2[N]); op==1 -> tanh epilogue.
__global__ __launch_bounds__(256) void gemm_nt(
    const float* __restrict__ A, const float* __restrict__ B, float* __restrict__ C,
    const float* __restrict__ b1, const float* __restrict__ b2,
    int M, int N, int K, int op)
{
    __shared__ __align__(16) float As[16][68];
    __shared__ __align__(16) float Bs[16][68];
    const int tid = threadIdx.x;
    const int bm = blockIdx.y * 64, bn = blockIdx.x * 64;
    const int lr = tid >> 2, lc = tid & 3;
    const int tm = tid & 15, tn = tid >> 4;
    float acc[4][4] = {};
    for (int k0 = 0; k0 < K; k0 += 16) {
        float4 a4 = *(const float4*)(A + (size_t)(bm + lr) * K + k0 + lc * 4);
        float4 b4 = *(const float4*)(B + (size_t)(bn + lr) * K + k0 + lc * 4);
        As[lc * 4 + 0][lr] = a4.x; As[lc * 4 + 1][lr] = a4.y;
        As[lc * 4 + 2][lr] = a4.z; As[lc * 4 + 3][lr] = a4.w;
        Bs[lc * 4 + 0][lr] = b4.x; Bs[lc * 4 + 1][lr] = b4.y;
        Bs[lc * 4 + 2][lr] = b4.z; Bs[lc * 4 + 3][lr] = b4.w;
        __syncthreads();
#pragma unroll
        for (int k = 0; k < 16; ++k) {
            const float4 av = *(const float4*)&As[k][tm * 4];
            const float4 bv = *(const float4*)&Bs[k][tn * 4];
            acc[0][0] += av.x * bv.x; acc[0][1] += av.x * bv.y; acc[0][2] += av.x * bv.z; acc[0][3] += av.x * bv.w;
            acc[1][0] += av.y * bv.x; acc[1][1] += av.y * bv.y; acc[1][2] += av.y * bv.z; acc[1][3] += av.y * bv.w;
            acc[2][0] += av.z * bv.x; acc[2][1] += av.z * bv.y; acc[2][2] += av.z * bv.z; acc[2][3] += av.z * bv.w;
            acc[3][0] += av.w * bv.x; acc[3][1] += av.w * bv.y; acc[3][2] += av.w * bv.z; acc[3][3] += av.w * bv.w;
        }
        __syncthreads();
    }
#pragma unroll
    for (int i = 0; i < 4; ++i) {
        const int r = bm + tm * 4 + i;
#pragma unroll
        for (int j = 0; j < 4; ++j) {
            const int cc = bn + tn * 4 + j;
            float v = acc[i][j] + b1[cc];
            if (b2) v += b2[cc];
            if (op == 1) v = tanh_fast(v);
            C[(size_t)r * N + cc] = v;
        }
    }
}

// ---------------------------------------------------------------------------
// Fence-free dataflow LSTM scan, one barrier per step.
// 3 chains x 32 slices = 96 WGs of 512 threads (8 waves).
// tid = out_j*32 + gate*8 + k  (out_j 0..15, gate 0..3, k 0..7).
// h exchanged as tagged (epoch<<32|f32_bits) u64 atomics at agent scope,
// PACKED (R5's line-padding backfired: 8x poll bytes, +HBM traffic).
// Poll: all 8 waves, exactly ONE u64 per lane, per-wave __all, s_sleep(1)
// backoff on retry only (tight spin saturates the coherence point - R4).
#define LDW(i) float4 q##i = wp[i];
#define SPL(i) float a##i##x = q##i.x, a##i##y = q##i.y, a##i##z = q##i.z, a##i##w = q##i.w;
#define PIN(i) asm volatile("" : "+v"(a##i##x), "+v"(a##i##y), "+v"(a##i##z), "+v"(a##i##w));
#define DOT(i) { float4 hv = hq[i]; \
    acc = fmaf(a##i##x, hv.x, acc); acc = fmaf(a##i##y, hv.y, acc); \
    acc = fmaf(a##i##z, hv.z, acc); acc = fmaf(a##i##w, hv.w, acc); }

__global__ __launch_bounds__(512, 2) void scan_kernel(
    const float* __restrict__ gx,   // [3][T][2048] x-part + both biases
    const float* __restrict__ whh0, const float* __restrict__ whh1, const float* __restrict__ whh2,
    const float* __restrict__ h00, const float* __restrict__ h01, const float* __restrict__ h02,
    const float* __restrict__ c00, const float* __restrict__ c01, const float* __restrict__ c02,
    u64* __restrict__ hbuf,         // [2][3][512] tagged pairs, pre-zeroed
    float* __restrict__ htop)       // [T][1536] pre-update h (stk|buf|hist)
{
    const int chain = blockIdx.x / NS;
    const int slice = blockIdx.x % NS;
    const int tid = threadIdx.x;
    const int out_j = tid >> 5;       // 0..15
    const int gate  = (tid >> 3) & 3; // 0..3 (i,f,g,o)
    const int k     = tid & 7;        // 64-col chunk
    const int row   = gate * HH + slice * 16 + out_j;   // gate row in whh
    const int lane  = tid & 63;
    const int lbase = lane & 32;

    const float* whh = (chain == 0) ? whh0 : (chain == 1) ? whh1 : whh2;
    const float* h0  = (chain == 0) ? h00  : (chain == 1) ? h01  : h02;
    const float* c0  = (chain == 0) ? c00  : (chain == 1) ? c01  : c02;
    const float* gxc = gx + (size_t)chain * TT * GG;

    // weight slice -> 64 named scalar floats
    const float4* wp = (const float4*)(whh + (size_t)row * HH + k * 64);
    LDW(0) LDW(1) LDW(2) LDW(3) LDW(4) LDW(5) LDW(6) LDW(7)
    LDW(8) LDW(9) LDW(10) LDW(11) LDW(12) LDW(13) LDW(14) LDW(15)
    SPL(0) SPL(1) SPL(2) SPL(3) SPL(4) SPL(5) SPL(6) SPL(7)
    SPL(8) SPL(9) SPL(10) SPL(11) SPL(12) SPL(13) SPL(14) SPL(15)

    float c_reg = 0.0f;
    if ((tid & 31) == 0) {
        c_reg = c0[slice * 16 + out_j];
        float hv = h0[slice * 16 + out_j];
        u64 pv = ((u64)1u << 32) | (u64)__float_as_uint(hv);   // tag 1 = ready for t=0
        __hip_atomic_store(&hbuf[(size_t)chain * HH + slice * 16 + out_j], pv,
                           __ATOMIC_RELAXED, __HIP_MEMORY_SCOPE_AGENT);
        htop[(size_t)chain * HH + slice * 16 + out_j] = hv;    // htop[0]
    }

    __shared__ float h_lds[2][8 * 68];   // parity double buffer, 68-float chunk stride

    // gx prefetch for t=0 (k==0 lanes carry gx for their gate row)
    float gxv = 0.0f;
    if (k == 0) gxv = gxc[row];

    for (int t = 0; t < TT; ++t) {
        // pin weights across the loop (defeat load-sinking)
        PIN(0) PIN(1) PIN(2) PIN(3) PIN(4) PIN(5) PIN(6) PIN(7)
        PIN(8) PIN(9) PIN(10) PIN(11) PIN(12) PIN(13) PIN(14) PIN(15)
        const int par = t & 1;

        // poll: all 8 waves, one tagged u64 per lane; sleep only on retry
        {
            const u64* src = hbuf + (size_t)(par * 3 + chain) * HH + tid;
            const unsigned need = (unsigned)(t + 1);
            u64 p = __hip_atomic_load(src, __ATOMIC_RELAXED, __HIP_MEMORY_SCOPE_AGENT);
            while (!__all((unsigned)(p >> 32) >= need)) {
                __builtin_amdgcn_s_sleep(1);
                p = __hip_atomic_load(src, __ATOMIC_RELAXED, __HIP_MEMORY_SCOPE_AGENT);
            }
            h_lds[par][(tid >> 6) * 68 + (tid & 63)] = __uint_as_float((unsigned)p);
        }
        __syncthreads();   // the ONLY barrier per step

        // dot: gate row x 64-col h chunk from LDS
        const float4* hq = (const float4*)(&h_lds[par][k * 68]);
        float acc = 0.0f;
        DOT(0) DOT(1) DOT(2) DOT(3) DOT(4) DOT(5) DOT(6) DOT(7)
        DOT(8) DOT(9) DOT(10) DOT(11) DOT(12) DOT(13) DOT(14) DOT(15)
        // butterfly over k (8 lanes per gate group)
        acc += __shfl_xor(acc, 1);
        acc += __shfl_xor(acc, 2);
        acc += __shfl_xor(acc, 4);
        if (k == 0) acc += gxv;
        // gather the 4 gate sums into the gate-0/k-0 lane (same wave)
        float gf = __shfl(acc, lbase + 8);
        float gg = __shfl(acc, lbase + 16);
        float go = __shfl(acc, lbase + 24);
        if ((tid & 31) == 0) {
            float c2 = sigm(gf) * c_reg + sigm(acc) * tanh_fast(gg);
            float h2 = sigm(go) * tanh_fast(c2);
            c_reg = c2;
            u64 pv = ((u64)(unsigned)(t + 2) << 32) | (u64)__float_as_uint(h2);
            __hip_atomic_store(&hbuf[(size_t)(((t + 1) & 1) * 3 + chain) * HH + slice * 16 + out_j],
                               pv, __ATOMIC_RELAXED, __HIP_MEMORY_SCOPE_AGENT);
            if (t + 1 < TT)
                htop[(size_t)(t + 1) * 1536 + chain * HH + slice * 16 + out_j] = h2;
        }
        // prefetch gx for t+1 (overlaps next poll; off the poll's first load)
        if (k == 0 && t + 1 < TT) gxv = gxc[(size_t)(t + 1) * GG + row];
    }
}

// ---------------------------------------------------------------------------
// per-row logits + log_softmax
__global__ __launch_bounds__(128) void k_logp(
    const float* __restrict__ summ, const float* __restrict__ Wo,
    const float* __restrict__ bo, float* __restrict__ out)
{
    __shared__ float srow[512];
    __shared__ float z[104];
    __shared__ float red[2];
    const int t = blockIdx.x, tid = threadIdx.x;
    ((float4*)srow)[tid] = ((const float4*)(summ + (size_t)t * 512))[tid];
    __syncthreads();
    if (tid < 100) {
        float a = bo[tid];
        const float* wr = Wo + (size_t)tid * 512;
        for (int k = 0; k < 512; k += 4)
            a += wr[k] * srow[k] + wr[k + 1] * srow[k + 1] + wr[k + 2] * srow[k + 2] + wr[k + 3] * srow[k + 3];
        z[tid] = a;
    }
    __syncthreads();
    if (tid < 64) {
        float m = z[tid];
        if (tid + 64 < 100) m = fmaxf(m, z[tid + 64]);
#pragma unroll
        for (int off = 32; off >= 1; off >>= 1) m = fmaxf(m, __shfl_xor(m, off, 64));
        float e = __expf(z[tid] - m) + ((tid + 64 < 100) ? __expf(z[tid + 64] - m) : 0.0f);
#pragma unroll
        for (int off = 32; off >= 1; off >>= 1) e += __shfl_xor(e, off, 64);
        if (tid == 0) { red[0] = m; red[1] = __logf(e); }
    }
    __syncthreads();
    if (tid < 100) out[(size_t)t * 100 + tid] = z[tid] - red[0] - red[1];
}

// ---------------------------------------------------------------------------
extern "C" void kernel_launch(void* const* d_in, const int* in_sizes, int n_in,
                              void* d_out, int out_size, void* d_ws, size_t ws_size,
                              hipStream_t stream)
{
    const int* words = (const int*)d_in[0];
    const int* pos   = (const int*)d_in[1];
    const int* acts  = (const int*)d_in[2];
    const float* wemb  = (const float*)d_in[3];
    const float* pemb  = (const float*)d_in[4];
    const float* aemb  = (const float*)d_in[5];
    const float* w2e_w = (const float*)d_in[6];
    const float* w2e_b = (const float*)d_in[7];
    const float* a2e_w = (const float*)d_in[8];
    const float* a2e_b = (const float*)d_in[9];
    const float* sum_w = (const float*)d_in[28];
    const float* sum_b = (const float*)d_in[29];
    const float* out_w = (const float*)d_in[30];
    const float* out_b = (const float*)d_in[31];

    float* ws = (float*)d_ws;
    float* xw   = ws;                                   // [4096*512]
    float* xa   = xw + (size_t)TT * HH;                 // [4096*512]
    float* gxp  = xa + (size_t)TT * HH;                 // [3][4096][2048]
    float* htop = gxp + (size_t)3 * TT * GG;            // [4096][1536]
    u64*   hbuf = (u64*)(htop + (size_t)TT * 3 * HH);   // [2][3][512] tagged pairs
    float* summary = xw;                                // alias: xw dead after Gx GEMMs

    (void)hipMemsetAsync(hbuf, 0, (size_t)2 * 3 * HH * sizeof(u64), stream);

    // Phase A: input projections
    k_xw<<<dim3(TT / 8), dim3(256), 0, stream>>>(words, pos, wemb, pemb, w2e_w, w2e_b, xw);
    k_xa<<<dim3(TT / 8), dim3(256), 0, stream>>>(acts, aemb, a2e_w, a2e_b, xa);

    // Phase A: Gx[c] = x_c @ wih_c^T + (bih_c + bhh_c)
    dim3 g2(GG / 64, TT / 64);
    gemm_nt<<<g2, dim3(256), 0, stream>>>(xw, (const float*)d_in[10], gxp,
                                          (const float*)d_in[12], (const float*)d_in[13],
                                          TT, GG, HH, 0);
    gemm_nt<<<g2, dim3(256), 0, stream>>>(xw, (const float*)d_in[16], gxp + (size_t)TT * GG,
                                          (const float*)d_in[18], (const float*)d_in[19],
                                          TT, GG, HH, 0);
    gemm_nt<<<g2, dim3(256), 0, stream>>>(xa, (const float*)d_in[22], gxp + (size_t)2 * TT * GG,
                                          (const float*)d_in[24], (const float*)d_in[25],
                                          TT, GG, HH, 0);

    // Phase B: dataflow scan (96 blocks of 512)
    scan_kernel<<<dim3(3 * NS), dim3(512), 0, stream>>>(
        gxp,
        (const float*)d_in[11], (const float*)d_in[17], (const float*)d_in[23],
        (const float*)d_in[14], (const float*)d_in[20], (const float*)d_in[26],
        (const float*)d_in[15], (const float*)d_in[21], (const float*)d_in[27],
        hbuf, htop);

    // Phase C: summary = tanh(Htop @ sum_w^T + sum_b); then logits + log_softmax
    dim3 g3(HH / 64, TT / 64);
    gemm_nt<<<g3, dim3(256), 0, stream>>>(htop, sum_w, summary, sum_b, nullptr,
                                          TT, HH, 3 * HH, 1);
    k_logp<<<dim3(TT), dim3(128), 0, stream>>>(summary, out_w, out_b, (float*)d_out);
}